// Round 5
// baseline (737.081 us; speedup 1.0000x reference)
//
#include <hip/hip_runtime.h>
#include <stdint.h>

// Problem constants (fixed by the reference)
#define NN 50000
#define EE 800000
#define FF 256
#define HH 256
#define LL 128

typedef __bf16 bf16x8 __attribute__((ext_vector_type(8)));
typedef float  f32x4  __attribute__((ext_vector_type(4)));
typedef float  f32x2  __attribute__((ext_vector_type(2)));

typedef __attribute__((address_space(1))) unsigned int uint_as1;
typedef __attribute__((address_space(3))) unsigned int uint_as3;

__device__ __forceinline__ unsigned short f2bf(float f) {
  union { float f; unsigned int u; } v; v.f = f;
  unsigned int u = v.u;
  u += 0x7FFFu + ((u >> 16) & 1u);   // RTNE (finite inputs only)
  return (unsigned short)(u >> 16);
}

__device__ __forceinline__ float bf2f(unsigned short u) {
  union { unsigned int u; float f; } v;
  v.u = ((unsigned int)u) << 16;
  return v.f;
}

__device__ __forceinline__ f32x4 bf4_to_f32(ushort4 u) {
  f32x4 r;
  r.x = bf2f(u.x); r.y = bf2f(u.y); r.z = bf2f(u.z); r.w = bf2f(u.w);
  return r;
}

__device__ __forceinline__ void gload_lds16(const void* g, void* l) {
  __builtin_amdgcn_global_load_lds((const uint_as1*)g, (uint_as3*)l, 16, 0, 0);
}

// ---------------- fused casts: features (vec) + 3 weight transpose-casts ----------------
// grid partition: [0,12500) features, [12500,12756) W1, [12756,13012) W2, [13012,13140) Wf
__global__ __launch_bounds__(256) void k_casts(const float* __restrict__ features,
                                               unsigned short* __restrict__ Xb,
                                               const float* __restrict__ W1,
                                               unsigned short* __restrict__ W1t,
                                               const float* __restrict__ W2,
                                               unsigned short* __restrict__ W2t,
                                               const float* __restrict__ Wf,
                                               unsigned short* __restrict__ Wft) {
  int b = blockIdx.x, t = threadIdx.x;
  if (b < 12500) {
    int i = b * 256 + t;  // n4 = 3,200,000 exactly
    f32x4 x = ((const f32x4*)features)[i];
    ushort4 o;
    o.x = f2bf(x.x); o.y = f2bf(x.y); o.z = f2bf(x.z); o.w = f2bf(x.w);
    ((ushort4*)Xb)[i] = o;
  } else if (b < 13012) {
    // W1 / W2: K=256, Nn=256, 65536 elems = 256 blocks each
    const float* in = (b < 12756) ? W1 : W2;
    unsigned short* out = (b < 12756) ? W1t : W2t;
    int i = ((b < 12756) ? (b - 12500) : (b - 12756)) * 256 + t;
    int n = i >> 8, k = i & 255;
    out[i] = f2bf(in[k * HH + n]);
  } else {
    // Wf: K=256 (HH), Nn=128 (LL), 32768 elems = 128 blocks
    int i = (b - 13012) * 256 + t;
    int n = i >> 8, k = i & 255;  // out is LL x HH (n in [0,128))
    Wft[i] = f2bf(Wf[k * LL + n]);
  }
}

// ---------------- CSR build ----------------
__global__ __launch_bounds__(256) void k_hist(const int* __restrict__ rows,
                                              int* __restrict__ cnt, int E) {
  int i = blockIdx.x * 256 + threadIdx.x;
  if (i < E) atomicAdd(&cnt[rows[i]], 1);
}

// Unordered exclusive allocation: wave-scan of counts + one global atomic per wave.
__global__ __launch_bounds__(256) void k_alloc(const int* __restrict__ cnt,
                                               int* __restrict__ cursor,
                                               int* __restrict__ total, int n) {
  int i = blockIdx.x * 256 + threadIdx.x;
  int lane = threadIdx.x & 63;
  int c = (i < n) ? cnt[i] : 0;
  int incl = c;
#pragma unroll
  for (int off = 1; off < 64; off <<= 1) {
    int v = __shfl_up(incl, off, 64);
    if (lane >= off) incl += v;
  }
  int excl = incl - c;
  int wtot = __shfl(incl, 63, 64);
  int base = 0;
  if (lane == 0) base = atomicAdd(total, wtot);
  base = __shfl(base, 0, 64);
  if (i < n) cursor[i] = base + excl;
}

__global__ __launch_bounds__(256) void k_fill(const int* __restrict__ rows,
                                              const int* __restrict__ cols,
                                              const float* __restrict__ vals,
                                              int* __restrict__ cursor,
                                              int2* __restrict__ csr, int E) {
  int i = blockIdx.x * 256 + threadIdx.x;
  if (i < E) {
    int p = atomicAdd(&cursor[rows[i]], 1);
    int2 pr;
    pr.x = cols[i];
    pr.y = __float_as_int(vals[i]);
    csr[p] = pr;
  }
}

// ---------------- SpMM (bf16 in / bf16 out), XCD-affine column chunking ----------------
// 8 column-chunks of 32; chunk = blockIdx % 8 so each XCD's L2 caches a 3.2 MB X-slice.
// Block = 4 waves; wave = 4 row-subgroups x 16 lanes; lane covers 2 cols (ushort2).
// After k_fill, cursor[row] == row end; start = end - cnt[row].
__global__ __launch_bounds__(256) void k_spmm(const unsigned short* __restrict__ X,
                                              const int* __restrict__ endp,
                                              const int* __restrict__ cnt,
                                              const int2* __restrict__ csr,
                                              unsigned short* __restrict__ Y, int n) {
  const int chunk = blockIdx.x & 7;
  const int rowblk = blockIdx.x >> 3;
  const int wave = threadIdx.x >> 6, lane = threadIdx.x & 63;
  const int subrow = lane >> 4, lane16 = lane & 15;
  const int row = rowblk * 16 + wave * 4 + subrow;
  if (row >= n) return;
  const int coff = chunk * 32 + lane16 * 2;  // 2 cols per lane
  int e = endp[row];
  int s = e - cnt[row];
  f32x2 a0 = {0.f, 0.f}, a1 = {0.f, 0.f};
  int p = s;
  for (; p + 1 < e; p += 2) {
    int2 e0 = csr[p], e1 = csr[p + 1];
    ushort2 x0 = *(const ushort2*)(X + (size_t)e0.x * HH + coff);
    ushort2 x1 = *(const ushort2*)(X + (size_t)e1.x * HH + coff);
    f32x2 v0; v0.x = bf2f(x0.x); v0.y = bf2f(x0.y);
    f32x2 v1; v1.x = bf2f(x1.x); v1.y = bf2f(x1.y);
    a0 += __int_as_float(e0.y) * v0;
    a1 += __int_as_float(e1.y) * v1;
  }
  if (p < e) {
    int2 e0 = csr[p];
    ushort2 x0 = *(const ushort2*)(X + (size_t)e0.x * HH + coff);
    f32x2 v0; v0.x = bf2f(x0.x); v0.y = bf2f(x0.y);
    a0 += __int_as_float(e0.y) * v0;
  }
  f32x2 a = a0 + a1;
  ushort2 o;
  o.x = f2bf(a.x); o.y = f2bf(a.y);
  *(ushort2*)(Y + (size_t)row * HH + coff) = o;
}

// ---------------- BatchNorm stats: row-per-wave ushort4 loads, LDS reduce ----------------
__global__ __launch_bounds__(256) void k_bnstats(const unsigned short* __restrict__ X,
                                                 float* __restrict__ sums, int n) {
  __shared__ float red[4][64][8];
  const int w = threadIdx.x >> 6, l = threadIdx.x & 63;
  f32x4 s = {0.f, 0.f, 0.f, 0.f}, s2 = {0.f, 0.f, 0.f, 0.f};
  for (int r = blockIdx.x * 4 + w; r < n; r += gridDim.x * 4) {
    f32x4 v = bf4_to_f32(((const ushort4*)(X + (size_t)r * HH))[l]);
    s += v;
    s2 += v * v;
  }
#pragma unroll
  for (int j = 0; j < 4; ++j) { red[w][l][j] = s[j]; red[w][l][4 + j] = s2[j]; }
  __syncthreads();
  if (threadIdx.x < 64) {
    int ll = threadIdx.x;
#pragma unroll
    for (int j = 0; j < 8; ++j) {
      float v = red[0][ll][j] + red[1][ll][j] + red[2][ll][j] + red[3][ll][j];
      int c = ll * 4 + (j & 3);
      atomicAdd(&sums[(j < 4 ? 0 : HH) + c], v);
    }
  }
}

// y = bf16(relu(x*scale + shift)); scale/shift computed per-block from raw sums
__global__ __launch_bounds__(256) void k_bnrc(const unsigned short* __restrict__ X,
                                              const float* __restrict__ sums,
                                              const float* __restrict__ g,
                                              const float* __restrict__ be,
                                              unsigned short* __restrict__ out, int n4) {
  __shared__ float sc[HH], sh[HH];
  int t = threadIdx.x;
  {
    float inv = 1.f / (float)NN;
    float mean = sums[t] * inv;
    float var = sums[HH + t] * inv - mean * mean;
    float s = g[t] * rsqrtf(var + 1e-5f);
    sc[t] = s;
    sh[t] = be[t] - mean * s;
  }
  __syncthreads();
  for (int i = blockIdx.x * 256 + t; i < n4; i += gridDim.x * 256) {
    f32x4 x = bf4_to_f32(((const ushort4*)X)[i]);
    int c0 = (i * 4) & (HH - 1);
    ushort4 o;
    o.x = f2bf(fmaxf(x.x * sc[c0 + 0] + sh[c0 + 0], 0.f));
    o.y = f2bf(fmaxf(x.y * sc[c0 + 1] + sh[c0 + 1], 0.f));
    o.z = f2bf(fmaxf(x.z * sc[c0 + 2] + sh[c0 + 2], 0.f));
    o.w = f2bf(fmaxf(x.w * sc[c0 + 3] + sh[c0 + 3], 0.f));
    ((ushort4*)out)[i] = o;
  }
}

// ---------------- GEMM: C(MxNn) = A(MxK,bf16) * Bt(NnxK,bf16)^T + bias ----------------
// 128x128 tile, BK=32, 4 waves (2x2), each wave 4x4 grid of 16x16x32 MFMAs.
// OUTB=1: write bf16; OUTB=0: write fp32. gather: A row remap (head on idx rows).
template <int OUTB>
__global__ __launch_bounds__(256, 2) void k_gemm(const unsigned short* __restrict__ A,
                                                 const unsigned short* __restrict__ Bt,
                                                 const float* __restrict__ bias,
                                                 void* __restrict__ Cv,
                                                 int M, int K, int Nn,
                                                 const int* __restrict__ gather) {
  __shared__ unsigned short lA[128 * 32];  // 8 KB, rows of 64B
  __shared__ unsigned short lB[128 * 32];  // 8 KB
  const int tid = threadIdx.x;
  const int wave = tid >> 6, lane = tid & 63;
  const int m0 = blockIdx.x * 128, n0 = blockIdx.y * 128;
  const int wm = (wave >> 1) * 64, wn = (wave & 1) * 64;
  const int lhi = lane >> 4, llo = lane & 15;

  // staging geometry: per issue a wave covers 16 rows x 32 cols (64B rows, 4 lanes/row)
  const int srow = wave * 16 + (lane >> 2);
  const int scol = (lane & 3) * 8;
  int ar0 = m0 + srow, ar1 = m0 + 64 + srow;
  ar0 = ar0 < M ? ar0 : 0;
  ar1 = ar1 < M ? ar1 : 0;
  if (gather) { ar0 = gather[ar0]; ar1 = gather[ar1]; }
  const unsigned short* pA0 = A + (size_t)ar0 * K + scol;
  const unsigned short* pA1 = A + (size_t)ar1 * K + scol;
  const unsigned short* pB0 = Bt + (size_t)(n0 + srow) * K + scol;
  const unsigned short* pB1 = Bt + (size_t)(n0 + 64 + srow) * K + scol;
  unsigned short* dA0 = lA + (wave * 16) * 32;
  unsigned short* dA1 = lA + (64 + wave * 16) * 32;
  unsigned short* dB0 = lB + (wave * 16) * 32;
  unsigned short* dB1 = lB + (64 + wave * 16) * 32;

  f32x4 zero = {0.f, 0.f, 0.f, 0.f};
  f32x4 acc[4][4];
#pragma unroll
  for (int i = 0; i < 4; ++i)
#pragma unroll
    for (int j = 0; j < 4; ++j) acc[i][j] = zero;

  for (int k0 = 0; k0 < K; k0 += 32) {
    gload_lds16(pA0 + k0, dA0);
    gload_lds16(pA1 + k0, dA1);
    gload_lds16(pB0 + k0, dB0);
    gload_lds16(pB1 + k0, dB1);
    __syncthreads();  // drains vmcnt -> LDS valid
    bf16x8 af[4], bfv[4];
#pragma unroll
    for (int mt = 0; mt < 4; ++mt)
      af[mt] = *(const bf16x8*)(lA + (wm + mt * 16 + llo) * 32 + lhi * 8);
#pragma unroll
    for (int nt = 0; nt < 4; ++nt)
      bfv[nt] = *(const bf16x8*)(lB + (wn + nt * 16 + llo) * 32 + lhi * 8);
#pragma unroll
    for (int mt = 0; mt < 4; ++mt)
#pragma unroll
      for (int nt = 0; nt < 4; ++nt)
        acc[mt][nt] = __builtin_amdgcn_mfma_f32_16x16x32_bf16(af[mt], bfv[nt], acc[mt][nt], 0, 0, 0);
    __syncthreads();  // all reads done before next stage
  }

#pragma unroll
  for (int nt = 0; nt < 4; ++nt) {
    int cn = n0 + wn + nt * 16 + llo;
    float bv = bias ? bias[cn] : 0.f;
#pragma unroll
    for (int mt = 0; mt < 4; ++mt) {
      int cm0 = m0 + wm + mt * 16 + lhi * 4;
#pragma unroll
      for (int r = 0; r < 4; ++r) {
        int cm = cm0 + r;
        if (cm < M) {
          float v = acc[mt][nt][r] + bv;
          if (OUTB)
            ((unsigned short*)Cv)[(size_t)cm * Nn + cn] = f2bf(v);
          else
            ((float*)Cv)[(size_t)cm * Nn + cn] = v;
        }
      }
    }
  }
}

extern "C" void kernel_launch(void* const* d_in, const int* in_sizes, int n_in,
                              void* d_out, int out_size, void* d_ws, size_t ws_size,
                              hipStream_t stream) {
  const float* features = (const float*)d_in[0];
  const float* edge_vals = (const float*)d_in[1];
  const float* W1 = (const float*)d_in[2];
  const float* db1 = (const float*)d_in[3];
  // d_in[4] = b1  — annihilated by training-mode BN (constant per column before mean-subtract)
  const float* g1 = (const float*)d_in[5];
  const float* be1 = (const float*)d_in[6];
  const float* W2 = (const float*)d_in[7];
  // d_in[8] = b2  — annihilated by BN
  const float* g2 = (const float*)d_in[9];
  const float* be2 = (const float*)d_in[10];
  const float* Wf = (const float*)d_in[11];
  const float* bfb = (const float*)d_in[12];
  const int* erows = (const int*)d_in[13];
  const int* ecols = (const int*)d_in[14];
  const int* idx = (const int*)d_in[15];
  const int M3 = in_sizes[15];
  (void)n_in; (void)out_size; (void)ws_size;

  char* ws = (char*)d_ws;
  size_t off = 0;
  auto alloc = [&](size_t bytes) -> void* {
    void* p = (void*)(ws + off);
    off += (bytes + 255) & ~(size_t)255;
    return p;
  };
  unsigned short* Xb = (unsigned short*)alloc((size_t)NN * HH * 2);  // features / hidden (bf16)
  unsigned short* Ab = (unsigned short*)alloc((size_t)NN * HH * 2);  // gemm out (bf16)
  unsigned short* Yb = (unsigned short*)alloc((size_t)NN * HH * 2);  // spmm out (bf16)
  unsigned short* W1t = (unsigned short*)alloc((size_t)FF * HH * 2);
  unsigned short* W2t = (unsigned short*)alloc((size_t)HH * HH * 2);
  unsigned short* Wft = (unsigned short*)alloc((size_t)HH * LL * 2);
  int* cursor = (int*)alloc((size_t)NN * 4);
  int* cnt = (int*)alloc((size_t)NN * 4);
  int2* csr = (int2*)alloc((size_t)EE * 8);
  float* stats = (float*)alloc(4 * HH * 4 + 256);  // sums1|sums2|total
  float* sums1 = stats;
  float* sums2 = stats + 2 * HH;
  int* total = (int*)(stats + 4 * HH);

  hipMemsetAsync(cnt, 0, (size_t)NN * 4, stream);
  hipMemsetAsync(stats, 0, 4 * HH * 4 + 256, stream);

  // all dtype conversions in one launch
  k_casts<<<13140, 256, 0, stream>>>(features, Xb, W1, W1t, W2, W2t, Wf, Wft);

  // CSR build (reused by both SpMMs); row bases via unordered atomic allocation
  k_hist<<<(EE + 255) / 256, 256, 0, stream>>>(erows, cnt, EE);
  k_alloc<<<(NN + 255) / 256, 256, 0, stream>>>(cnt, cursor, total, NN);
  k_fill<<<(EE + 255) / 256, 256, 0, stream>>>(erows, ecols, edge_vals, cursor, csr, EE);
  // after k_fill: cursor[row] == row end

  const int spmm_blocks = ((NN + 15) / 16) * 8;  // 3125 row-blocks x 8 col-chunks

  // layer 1
  k_gemm<1><<<dim3((NN + 127) / 128, HH / 128), 256, 0, stream>>>(Xb, W1t, db1, Ab, NN, FF, HH, nullptr);
  k_spmm<<<spmm_blocks, 256, 0, stream>>>(Ab, cursor, cnt, csr, Yb, NN);
  k_bnstats<<<1024, 256, 0, stream>>>(Yb, sums1, NN);
  k_bnrc<<<2048, 256, 0, stream>>>(Yb, sums1, g1, be1, Xb, NN * HH / 4);

  // layer 2
  k_gemm<1><<<dim3((NN + 127) / 128, HH / 128), 256, 0, stream>>>(Xb, W2t, nullptr, Ab, NN, HH, HH, nullptr);
  k_spmm<<<spmm_blocks, 256, 0, stream>>>(Ab, cursor, cnt, csr, Yb, NN);
  k_bnstats<<<1024, 256, 0, stream>>>(Yb, sums2, NN);
  k_bnrc<<<2048, 256, 0, stream>>>(Yb, sums2, g2, be2, Xb, NN * HH / 4);

  // head: only idx rows, C = H[idx] @ Wf + bf
  k_gemm<0><<<dim3((M3 + 127) / 128, LL / 128), 256, 0, stream>>>(Xb, Wft, bfb, d_out, M3, HH, LL, idx);
}

// Round 6
// 630.513 us; speedup vs baseline: 1.1690x; 1.1690x over previous
//
#include <hip/hip_runtime.h>
#include <stdint.h>

// Problem constants (fixed by the reference)
#define NN 50000
#define EE 800000
#define FF 256
#define HH 256
#define LL 128

typedef __bf16 bf16x8 __attribute__((ext_vector_type(8)));
typedef float  f32x4  __attribute__((ext_vector_type(4)));

typedef __attribute__((address_space(1))) unsigned int uint_as1;
typedef __attribute__((address_space(3))) unsigned int uint_as3;

__device__ __forceinline__ unsigned short f2bf(float f) {
  union { float f; unsigned int u; } v; v.f = f;
  unsigned int u = v.u;
  u += 0x7FFFu + ((u >> 16) & 1u);   // RTNE (finite inputs only)
  return (unsigned short)(u >> 16);
}

__device__ __forceinline__ float bf2f(unsigned short u) {
  union { unsigned int u; float f; } v;
  v.u = ((unsigned int)u) << 16;
  return v.f;
}

__device__ __forceinline__ f32x4 bf4_to_f32(ushort4 u) {
  f32x4 r;
  r.x = bf2f(u.x); r.y = bf2f(u.y); r.z = bf2f(u.z); r.w = bf2f(u.w);
  return r;
}

__device__ __forceinline__ void gload_lds16(const void* g, void* l) {
  __builtin_amdgcn_global_load_lds((const uint_as1*)g, (uint_as3*)l, 16, 0, 0);
}

// ---------------- fused casts: features (vec) + 3 weight transpose-casts ----------------
// grid partition: [0,12500) features, [12500,12756) W1, [12756,13012) W2, [13012,13140) Wf
__global__ __launch_bounds__(256) void k_casts(const float* __restrict__ features,
                                               unsigned short* __restrict__ Xb,
                                               const float* __restrict__ W1,
                                               unsigned short* __restrict__ W1t,
                                               const float* __restrict__ W2,
                                               unsigned short* __restrict__ W2t,
                                               const float* __restrict__ Wf,
                                               unsigned short* __restrict__ Wft) {
  int b = blockIdx.x, t = threadIdx.x;
  if (b < 12500) {
    int i = b * 256 + t;  // n4 = 3,200,000 exactly
    f32x4 x = ((const f32x4*)features)[i];
    ushort4 o;
    o.x = f2bf(x.x); o.y = f2bf(x.y); o.z = f2bf(x.z); o.w = f2bf(x.w);
    ((ushort4*)Xb)[i] = o;
  } else if (b < 13012) {
    // W1 / W2: K=256, Nn=256, 65536 elems = 256 blocks each
    const float* in = (b < 12756) ? W1 : W2;
    unsigned short* out = (b < 12756) ? W1t : W2t;
    int i = ((b < 12756) ? (b - 12500) : (b - 12756)) * 256 + t;
    int n = i >> 8, k = i & 255;
    out[i] = f2bf(in[k * HH + n]);
  } else {
    // Wf: K=256 (HH), Nn=128 (LL), 32768 elems = 128 blocks
    int i = (b - 13012) * 256 + t;
    int n = i >> 8, k = i & 255;  // out is LL x HH (n in [0,128))
    Wft[i] = f2bf(Wf[k * LL + n]);
  }
}

// ---------------- CSR build ----------------
__global__ __launch_bounds__(256) void k_hist(const int* __restrict__ rows,
                                              int* __restrict__ cnt, int E) {
  int i = blockIdx.x * 256 + threadIdx.x;
  if (i < E) atomicAdd(&cnt[rows[i]], 1);
}

// Unordered exclusive allocation: wave-scan of counts + one global atomic per wave.
__global__ __launch_bounds__(256) void k_alloc(const int* __restrict__ cnt,
                                               int* __restrict__ cursor,
                                               int* __restrict__ total, int n) {
  int i = blockIdx.x * 256 + threadIdx.x;
  int lane = threadIdx.x & 63;
  int c = (i < n) ? cnt[i] : 0;
  int incl = c;
#pragma unroll
  for (int off = 1; off < 64; off <<= 1) {
    int v = __shfl_up(incl, off, 64);
    if (lane >= off) incl += v;
  }
  int excl = incl - c;
  int wtot = __shfl(incl, 63, 64);
  int base = 0;
  if (lane == 0) base = atomicAdd(total, wtot);
  base = __shfl(base, 0, 64);
  if (i < n) cursor[i] = base + excl;
}

// CSR entry packed to 4B: (col << 16) | bf16(val). col < 50000 < 65536.
__global__ __launch_bounds__(256) void k_fill(const int* __restrict__ rows,
                                              const int* __restrict__ cols,
                                              const float* __restrict__ vals,
                                              int* __restrict__ cursor,
                                              unsigned int* __restrict__ csr, int E) {
  int i = blockIdx.x * 256 + threadIdx.x;
  if (i < E) {
    int p = atomicAdd(&cursor[rows[i]], 1);
    csr[p] = ((unsigned int)cols[i] << 16) | (unsigned int)f2bf(vals[i]);
  }
}

// ---------------- SpMM (bf16 in / bf16 out): Y[i] = sum_e val*X[col] ----------------
// One wave per row (lane = ushort4 -> full 512B row per gather), 8 edge streams in
// flight. After k_fill, cursor[row] == row end; start = end - cnt[row].
__global__ __launch_bounds__(256) void k_spmm(const unsigned short* __restrict__ X,
                                              const int* __restrict__ endp,
                                              const int* __restrict__ cnt,
                                              const unsigned int* __restrict__ csr,
                                              unsigned short* __restrict__ Y, int n) {
  int row = blockIdx.x * 4 + (threadIdx.x >> 6);
  int lane = threadIdx.x & 63;
  if (row >= n) return;
  int e = endp[row];
  int s = e - cnt[row];
  f32x4 a0 = {0.f, 0.f, 0.f, 0.f};
  f32x4 a1 = a0, a2 = a0, a3 = a0, a4 = a0, a5 = a0, a6 = a0, a7 = a0;
  int p = s;
  int e8 = s + ((e - s) & ~7);
  for (; p < e8; p += 8) {
    unsigned int c0 = csr[p + 0], c1 = csr[p + 1], c2 = csr[p + 2], c3 = csr[p + 3];
    unsigned int c4 = csr[p + 4], c5 = csr[p + 5], c6 = csr[p + 6], c7 = csr[p + 7];
    ushort4 x0 = ((const ushort4*)(X + (size_t)(c0 >> 16) * HH))[lane];
    ushort4 x1 = ((const ushort4*)(X + (size_t)(c1 >> 16) * HH))[lane];
    ushort4 x2 = ((const ushort4*)(X + (size_t)(c2 >> 16) * HH))[lane];
    ushort4 x3 = ((const ushort4*)(X + (size_t)(c3 >> 16) * HH))[lane];
    ushort4 x4 = ((const ushort4*)(X + (size_t)(c4 >> 16) * HH))[lane];
    ushort4 x5 = ((const ushort4*)(X + (size_t)(c5 >> 16) * HH))[lane];
    ushort4 x6 = ((const ushort4*)(X + (size_t)(c6 >> 16) * HH))[lane];
    ushort4 x7 = ((const ushort4*)(X + (size_t)(c7 >> 16) * HH))[lane];
    a0 += bf2f((unsigned short)c0) * bf4_to_f32(x0);
    a1 += bf2f((unsigned short)c1) * bf4_to_f32(x1);
    a2 += bf2f((unsigned short)c2) * bf4_to_f32(x2);
    a3 += bf2f((unsigned short)c3) * bf4_to_f32(x3);
    a4 += bf2f((unsigned short)c4) * bf4_to_f32(x4);
    a5 += bf2f((unsigned short)c5) * bf4_to_f32(x5);
    a6 += bf2f((unsigned short)c6) * bf4_to_f32(x6);
    a7 += bf2f((unsigned short)c7) * bf4_to_f32(x7);
  }
  for (; p < e; ++p) {
    unsigned int c0 = csr[p];
    ushort4 x0 = ((const ushort4*)(X + (size_t)(c0 >> 16) * HH))[lane];
    a0 += bf2f((unsigned short)c0) * bf4_to_f32(x0);
  }
  f32x4 a = ((a0 + a1) + (a2 + a3)) + ((a4 + a5) + (a6 + a7));
  ushort4 o;
  o.x = f2bf(a.x); o.y = f2bf(a.y); o.z = f2bf(a.z); o.w = f2bf(a.w);
  ((ushort4*)(Y + (size_t)row * HH))[lane] = o;
}

// ---------------- BatchNorm stats: row-per-wave ushort4 loads, LDS reduce ----------------
__global__ __launch_bounds__(256) void k_bnstats(const unsigned short* __restrict__ X,
                                                 float* __restrict__ sums, int n) {
  __shared__ float red[4][64][8];
  const int w = threadIdx.x >> 6, l = threadIdx.x & 63;
  f32x4 s = {0.f, 0.f, 0.f, 0.f}, s2 = {0.f, 0.f, 0.f, 0.f};
  for (int r = blockIdx.x * 4 + w; r < n; r += gridDim.x * 4) {
    f32x4 v = bf4_to_f32(((const ushort4*)(X + (size_t)r * HH))[l]);
    s += v;
    s2 += v * v;
  }
#pragma unroll
  for (int j = 0; j < 4; ++j) { red[w][l][j] = s[j]; red[w][l][4 + j] = s2[j]; }
  __syncthreads();
  if (threadIdx.x < 64) {
    int ll = threadIdx.x;
#pragma unroll
    for (int j = 0; j < 8; ++j) {
      float v = red[0][ll][j] + red[1][ll][j] + red[2][ll][j] + red[3][ll][j];
      int c = ll * 4 + (j & 3);
      atomicAdd(&sums[(j < 4 ? 0 : HH) + c], v);
    }
  }
}

// y = bf16(relu(x*scale + shift)); scale/shift computed per-block from raw sums
__global__ __launch_bounds__(256) void k_bnrc(const unsigned short* __restrict__ X,
                                              const float* __restrict__ sums,
                                              const float* __restrict__ g,
                                              const float* __restrict__ be,
                                              unsigned short* __restrict__ out, int n4) {
  __shared__ float sc[HH], sh[HH];
  int t = threadIdx.x;
  {
    float inv = 1.f / (float)NN;
    float mean = sums[t] * inv;
    float var = sums[HH + t] * inv - mean * mean;
    float s = g[t] * rsqrtf(var + 1e-5f);
    sc[t] = s;
    sh[t] = be[t] - mean * s;
  }
  __syncthreads();
  for (int i = blockIdx.x * 256 + t; i < n4; i += gridDim.x * 256) {
    f32x4 x = bf4_to_f32(((const ushort4*)X)[i]);
    int c0 = (i * 4) & (HH - 1);
    ushort4 o;
    o.x = f2bf(fmaxf(x.x * sc[c0 + 0] + sh[c0 + 0], 0.f));
    o.y = f2bf(fmaxf(x.y * sc[c0 + 1] + sh[c0 + 1], 0.f));
    o.z = f2bf(fmaxf(x.z * sc[c0 + 2] + sh[c0 + 2], 0.f));
    o.w = f2bf(fmaxf(x.w * sc[c0 + 3] + sh[c0 + 3], 0.f));
    ((ushort4*)out)[i] = o;
  }
}

// ---------------- GEMM: C(MxNn) = A(MxK,bf16) * Bt(NnxK,bf16)^T + bias ----------------
// 128x128 tile, BK=32, 4 waves (2x2), each wave 4x4 grid of 16x16x32 MFMAs.
// OUTB=1: write bf16; OUTB=0: write fp32. gather: A row remap (head on idx rows).
template <int OUTB>
__global__ __launch_bounds__(256, 2) void k_gemm(const unsigned short* __restrict__ A,
                                                 const unsigned short* __restrict__ Bt,
                                                 const float* __restrict__ bias,
                                                 void* __restrict__ Cv,
                                                 int M, int K, int Nn,
                                                 const int* __restrict__ gather) {
  __shared__ unsigned short lA[128 * 32];  // 8 KB, rows of 64B
  __shared__ unsigned short lB[128 * 32];  // 8 KB
  const int tid = threadIdx.x;
  const int wave = tid >> 6, lane = tid & 63;
  const int m0 = blockIdx.x * 128, n0 = blockIdx.y * 128;
  const int wm = (wave >> 1) * 64, wn = (wave & 1) * 64;
  const int lhi = lane >> 4, llo = lane & 15;

  // staging geometry: per issue a wave covers 16 rows x 32 cols (64B rows, 4 lanes/row)
  const int srow = wave * 16 + (lane >> 2);
  const int scol = (lane & 3) * 8;
  int ar0 = m0 + srow, ar1 = m0 + 64 + srow;
  ar0 = ar0 < M ? ar0 : 0;
  ar1 = ar1 < M ? ar1 : 0;
  if (gather) { ar0 = gather[ar0]; ar1 = gather[ar1]; }
  const unsigned short* pA0 = A + (size_t)ar0 * K + scol;
  const unsigned short* pA1 = A + (size_t)ar1 * K + scol;
  const unsigned short* pB0 = Bt + (size_t)(n0 + srow) * K + scol;
  const unsigned short* pB1 = Bt + (size_t)(n0 + 64 + srow) * K + scol;
  unsigned short* dA0 = lA + (wave * 16) * 32;
  unsigned short* dA1 = lA + (64 + wave * 16) * 32;
  unsigned short* dB0 = lB + (wave * 16) * 32;
  unsigned short* dB1 = lB + (64 + wave * 16) * 32;

  f32x4 zero = {0.f, 0.f, 0.f, 0.f};
  f32x4 acc[4][4];
#pragma unroll
  for (int i = 0; i < 4; ++i)
#pragma unroll
    for (int j = 0; j < 4; ++j) acc[i][j] = zero;

  for (int k0 = 0; k0 < K; k0 += 32) {
    gload_lds16(pA0 + k0, dA0);
    gload_lds16(pA1 + k0, dA1);
    gload_lds16(pB0 + k0, dB0);
    gload_lds16(pB1 + k0, dB1);
    __syncthreads();  // drains vmcnt -> LDS valid
    bf16x8 af[4], bfv[4];
#pragma unroll
    for (int mt = 0; mt < 4; ++mt)
      af[mt] = *(const bf16x8*)(lA + (wm + mt * 16 + llo) * 32 + lhi * 8);
#pragma unroll
    for (int nt = 0; nt < 4; ++nt)
      bfv[nt] = *(const bf16x8*)(lB + (wn + nt * 16 + llo) * 32 + lhi * 8);
#pragma unroll
    for (int mt = 0; mt < 4; ++mt)
#pragma unroll
      for (int nt = 0; nt < 4; ++nt)
        acc[mt][nt] = __builtin_amdgcn_mfma_f32_16x16x32_bf16(af[mt], bfv[nt], acc[mt][nt], 0, 0, 0);
    __syncthreads();  // all reads done before next stage
  }

#pragma unroll
  for (int nt = 0; nt < 4; ++nt) {
    int cn = n0 + wn + nt * 16 + llo;
    float bv = bias ? bias[cn] : 0.f;
#pragma unroll
    for (int mt = 0; mt < 4; ++mt) {
      int cm0 = m0 + wm + mt * 16 + lhi * 4;
#pragma unroll
      for (int r = 0; r < 4; ++r) {
        int cm = cm0 + r;
        if (cm < M) {
          float v = acc[mt][nt][r] + bv;
          if (OUTB)
            ((unsigned short*)Cv)[(size_t)cm * Nn + cn] = f2bf(v);
          else
            ((float*)Cv)[(size_t)cm * Nn + cn] = v;
        }
      }
    }
  }
}

extern "C" void kernel_launch(void* const* d_in, const int* in_sizes, int n_in,
                              void* d_out, int out_size, void* d_ws, size_t ws_size,
                              hipStream_t stream) {
  const float* features = (const float*)d_in[0];
  const float* edge_vals = (const float*)d_in[1];
  const float* W1 = (const float*)d_in[2];
  const float* db1 = (const float*)d_in[3];
  // d_in[4] = b1  — annihilated by training-mode BN (constant per column before mean-subtract)
  const float* g1 = (const float*)d_in[5];
  const float* be1 = (const float*)d_in[6];
  const float* W2 = (const float*)d_in[7];
  // d_in[8] = b2  — annihilated by BN
  const float* g2 = (const float*)d_in[9];
  const float* be2 = (const float*)d_in[10];
  const float* Wf = (const float*)d_in[11];
  const float* bfb = (const float*)d_in[12];
  const int* erows = (const int*)d_in[13];
  const int* ecols = (const int*)d_in[14];
  const int* idx = (const int*)d_in[15];
  const int M3 = in_sizes[15];
  (void)n_in; (void)out_size; (void)ws_size;

  char* ws = (char*)d_ws;
  size_t off = 0;
  auto alloc = [&](size_t bytes) -> void* {
    void* p = (void*)(ws + off);
    off += (bytes + 255) & ~(size_t)255;
    return p;
  };
  unsigned short* Xb = (unsigned short*)alloc((size_t)NN * HH * 2);  // features / hidden (bf16)
  unsigned short* Ab = (unsigned short*)alloc((size_t)NN * HH * 2);  // gemm out (bf16)
  unsigned short* Yb = (unsigned short*)alloc((size_t)NN * HH * 2);  // spmm out (bf16)
  unsigned short* W1t = (unsigned short*)alloc((size_t)FF * HH * 2);
  unsigned short* W2t = (unsigned short*)alloc((size_t)HH * HH * 2);
  unsigned short* Wft = (unsigned short*)alloc((size_t)HH * LL * 2);
  int* cursor = (int*)alloc((size_t)NN * 4);
  int* cnt = (int*)alloc((size_t)NN * 4);
  unsigned int* csr = (unsigned int*)alloc((size_t)EE * 4);
  float* stats = (float*)alloc(4 * HH * 4 + 256);  // sums1|sums2|total
  float* sums1 = stats;
  float* sums2 = stats + 2 * HH;
  int* total = (int*)(stats + 4 * HH);

  hipMemsetAsync(cnt, 0, (size_t)NN * 4, stream);
  hipMemsetAsync(stats, 0, 4 * HH * 4 + 256, stream);

  // all dtype conversions in one launch
  k_casts<<<13140, 256, 0, stream>>>(features, Xb, W1, W1t, W2, W2t, Wf, Wft);

  // CSR build (reused by both SpMMs); row bases via unordered atomic allocation
  k_hist<<<(EE + 255) / 256, 256, 0, stream>>>(erows, cnt, EE);
  k_alloc<<<(NN + 255) / 256, 256, 0, stream>>>(cnt, cursor, total, NN);
  k_fill<<<(EE + 255) / 256, 256, 0, stream>>>(erows, ecols, edge_vals, cursor, csr, EE);
  // after k_fill: cursor[row] == row end

  // layer 1
  k_gemm<1><<<dim3((NN + 127) / 128, HH / 128), 256, 0, stream>>>(Xb, W1t, db1, Ab, NN, FF, HH, nullptr);
  k_spmm<<<(NN + 3) / 4, 256, 0, stream>>>(Ab, cursor, cnt, csr, Yb, NN);
  k_bnstats<<<1024, 256, 0, stream>>>(Yb, sums1, NN);
  k_bnrc<<<2048, 256, 0, stream>>>(Yb, sums1, g1, be1, Xb, NN * HH / 4);

  // layer 2
  k_gemm<1><<<dim3((NN + 127) / 128, HH / 128), 256, 0, stream>>>(Xb, W2t, nullptr, Ab, NN, HH, HH, nullptr);
  k_spmm<<<(NN + 3) / 4, 256, 0, stream>>>(Ab, cursor, cnt, csr, Yb, NN);
  k_bnstats<<<1024, 256, 0, stream>>>(Yb, sums2, NN);
  k_bnrc<<<2048, 256, 0, stream>>>(Yb, sums2, g2, be2, Xb, NN * HH / 4);

  // head: only idx rows, C = H[idx] @ Wf + bf
  k_gemm<0><<<dim3((M3 + 127) / 128, LL / 128), 256, 0, stream>>>(Xb, Wft, bfb, d_out, M3, HH, LL, idx);
}

// Round 7
// 463.053 us; speedup vs baseline: 1.5918x; 1.3616x over previous
//
#include <hip/hip_runtime.h>
#include <stdint.h>

// Problem constants (fixed by the reference)
#define NN 50000
#define EE 800000
#define FF 256
#define HH 256
#define LL 128
#define SBLK 512   // bnstats stage-A blocks

typedef __bf16 bf16x8 __attribute__((ext_vector_type(8)));
typedef float  f32x4  __attribute__((ext_vector_type(4)));

typedef __attribute__((address_space(1))) unsigned int uint_as1;
typedef __attribute__((address_space(3))) unsigned int uint_as3;

__device__ __forceinline__ unsigned short f2bf(float f) {
  union { float f; unsigned int u; } v; v.f = f;
  unsigned int u = v.u;
  u += 0x7FFFu + ((u >> 16) & 1u);   // RTNE (finite inputs only)
  return (unsigned short)(u >> 16);
}

__device__ __forceinline__ float bf2f(unsigned short u) {
  union { unsigned int u; float f; } v;
  v.u = ((unsigned int)u) << 16;
  return v.f;
}

__device__ __forceinline__ f32x4 bf4_to_f32(ushort4 u) {
  f32x4 r;
  r.x = bf2f(u.x); r.y = bf2f(u.y); r.z = bf2f(u.z); r.w = bf2f(u.w);
  return r;
}

__device__ __forceinline__ void gload_lds16(const void* g, void* l) {
  __builtin_amdgcn_global_load_lds((const uint_as1*)g, (uint_as3*)l, 16, 0, 0);
}

// ---------------- fused casts: features (vec) + 3 weight transpose-casts ----------------
// grid partition: [0,12500) features, [12500,12756) W1, [12756,13012) W2, [13012,13140) Wf
__global__ __launch_bounds__(256) void k_casts(const float* __restrict__ features,
                                               unsigned short* __restrict__ Xb,
                                               const float* __restrict__ W1,
                                               unsigned short* __restrict__ W1t,
                                               const float* __restrict__ W2,
                                               unsigned short* __restrict__ W2t,
                                               const float* __restrict__ Wf,
                                               unsigned short* __restrict__ Wft) {
  int b = blockIdx.x, t = threadIdx.x;
  if (b < 12500) {
    int i = b * 256 + t;  // n4 = 3,200,000 exactly
    f32x4 x = ((const f32x4*)features)[i];
    ushort4 o;
    o.x = f2bf(x.x); o.y = f2bf(x.y); o.z = f2bf(x.z); o.w = f2bf(x.w);
    ((ushort4*)Xb)[i] = o;
  } else if (b < 13012) {
    // W1 / W2: K=256, Nn=256, 65536 elems = 256 blocks each
    const float* in = (b < 12756) ? W1 : W2;
    unsigned short* out = (b < 12756) ? W1t : W2t;
    int i = ((b < 12756) ? (b - 12500) : (b - 12756)) * 256 + t;
    int n = i >> 8, k = i & 255;
    out[i] = f2bf(in[k * HH + n]);
  } else {
    // Wf: K=256 (HH), Nn=128 (LL), 32768 elems = 128 blocks
    int i = (b - 13012) * 256 + t;
    int n = i >> 8, k = i & 255;  // out is LL x HH (n in [0,128))
    Wft[i] = f2bf(Wf[k * LL + n]);
  }
}

// ---------------- CSR build ----------------
__global__ __launch_bounds__(256) void k_hist(const int* __restrict__ rows,
                                              int* __restrict__ cnt, int E) {
  int i = blockIdx.x * 256 + threadIdx.x;
  if (i < E) atomicAdd(&cnt[rows[i]], 1);
}

// Unordered exclusive allocation: wave-scan of counts + one global atomic per wave.
__global__ __launch_bounds__(256) void k_alloc(const int* __restrict__ cnt,
                                               int* __restrict__ cursor,
                                               int* __restrict__ total, int n) {
  int i = blockIdx.x * 256 + threadIdx.x;
  int lane = threadIdx.x & 63;
  int c = (i < n) ? cnt[i] : 0;
  int incl = c;
#pragma unroll
  for (int off = 1; off < 64; off <<= 1) {
    int v = __shfl_up(incl, off, 64);
    if (lane >= off) incl += v;
  }
  int excl = incl - c;
  int wtot = __shfl(incl, 63, 64);
  int base = 0;
  if (lane == 0) base = atomicAdd(total, wtot);
  base = __shfl(base, 0, 64);
  if (i < n) cursor[i] = base + excl;
}

// CSR entry packed to 4B: (col << 16) | bf16(val). col < 50000 < 65536.
__global__ __launch_bounds__(256) void k_fill(const int* __restrict__ rows,
                                              const int* __restrict__ cols,
                                              const float* __restrict__ vals,
                                              int* __restrict__ cursor,
                                              unsigned int* __restrict__ csr, int E) {
  int i = blockIdx.x * 256 + threadIdx.x;
  if (i < E) {
    int p = atomicAdd(&cursor[rows[i]], 1);
    csr[p] = ((unsigned int)cols[i] << 16) | (unsigned int)f2bf(vals[i]);
  }
}

// ---------------- SpMM (bf16 in / bf16 out): Y[i] = sum_e val*X[col] ----------------
// One wave per row (lane = ushort4 -> full 512B row per gather), 8 edge streams in
// flight. After k_fill, cursor[row] == row end; start = end - cnt[row].
__global__ __launch_bounds__(256) void k_spmm(const unsigned short* __restrict__ X,
                                              const int* __restrict__ endp,
                                              const int* __restrict__ cnt,
                                              const unsigned int* __restrict__ csr,
                                              unsigned short* __restrict__ Y, int n) {
  int row = blockIdx.x * 4 + (threadIdx.x >> 6);
  int lane = threadIdx.x & 63;
  if (row >= n) return;
  int e = endp[row];
  int s = e - cnt[row];
  f32x4 a0 = {0.f, 0.f, 0.f, 0.f};
  f32x4 a1 = a0, a2 = a0, a3 = a0, a4 = a0, a5 = a0, a6 = a0, a7 = a0;
  int p = s;
  int e8 = s + ((e - s) & ~7);
  for (; p < e8; p += 8) {
    unsigned int c0 = csr[p + 0], c1 = csr[p + 1], c2 = csr[p + 2], c3 = csr[p + 3];
    unsigned int c4 = csr[p + 4], c5 = csr[p + 5], c6 = csr[p + 6], c7 = csr[p + 7];
    ushort4 x0 = ((const ushort4*)(X + (size_t)(c0 >> 16) * HH))[lane];
    ushort4 x1 = ((const ushort4*)(X + (size_t)(c1 >> 16) * HH))[lane];
    ushort4 x2 = ((const ushort4*)(X + (size_t)(c2 >> 16) * HH))[lane];
    ushort4 x3 = ((const ushort4*)(X + (size_t)(c3 >> 16) * HH))[lane];
    ushort4 x4 = ((const ushort4*)(X + (size_t)(c4 >> 16) * HH))[lane];
    ushort4 x5 = ((const ushort4*)(X + (size_t)(c5 >> 16) * HH))[lane];
    ushort4 x6 = ((const ushort4*)(X + (size_t)(c6 >> 16) * HH))[lane];
    ushort4 x7 = ((const ushort4*)(X + (size_t)(c7 >> 16) * HH))[lane];
    a0 += bf2f((unsigned short)c0) * bf4_to_f32(x0);
    a1 += bf2f((unsigned short)c1) * bf4_to_f32(x1);
    a2 += bf2f((unsigned short)c2) * bf4_to_f32(x2);
    a3 += bf2f((unsigned short)c3) * bf4_to_f32(x3);
    a4 += bf2f((unsigned short)c4) * bf4_to_f32(x4);
    a5 += bf2f((unsigned short)c5) * bf4_to_f32(x5);
    a6 += bf2f((unsigned short)c6) * bf4_to_f32(x6);
    a7 += bf2f((unsigned short)c7) * bf4_to_f32(x7);
  }
  for (; p < e; ++p) {
    unsigned int c0 = csr[p];
    ushort4 x0 = ((const ushort4*)(X + (size_t)(c0 >> 16) * HH))[lane];
    a0 += bf2f((unsigned short)c0) * bf4_to_f32(x0);
  }
  f32x4 a = ((a0 + a1) + (a2 + a3)) + ((a4 + a5) + (a6 + a7));
  ushort4 o;
  o.x = f2bf(a.x); o.y = f2bf(a.y); o.z = f2bf(a.z); o.w = f2bf(a.w);
  ((ushort4*)(Y + (size_t)row * HH))[lane] = o;
}

// ---------------- BatchNorm stats, two-stage (atomic-free) ----------------
// Stage A: SBLK blocks; wave-per-4-rows ushort4 loads; LDS reduce (stride-9 pad:
// 2 lanes/bank = conflict-free); block writes 512 partials contiguously.
// part layout: [stat(2)][block(SBLK)][col(256)]
__global__ __launch_bounds__(256) void k_bnstats(const unsigned short* __restrict__ X,
                                                 float* __restrict__ part, int n) {
  __shared__ float red[4][64][9];
  const int w = threadIdx.x >> 6, l = threadIdx.x & 63;
  f32x4 s = {0.f, 0.f, 0.f, 0.f}, s2 = {0.f, 0.f, 0.f, 0.f};
  for (int r = blockIdx.x * 4 + w; r < n; r += gridDim.x * 4) {
    f32x4 v = bf4_to_f32(((const ushort4*)(X + (size_t)r * HH))[l]);
    s += v;
    s2 += v * v;
  }
#pragma unroll
  for (int j = 0; j < 4; ++j) { red[w][l][j] = s[j]; red[w][l][4 + j] = s2[j]; }
  __syncthreads();
  if (threadIdx.x < 64) {
    int ll = threadIdx.x;
#pragma unroll
    for (int j = 0; j < 8; ++j) {
      float v = red[0][ll][j] + red[1][ll][j] + red[2][ll][j] + red[3][ll][j];
      int c = ll * 4 + (j & 3);
      part[((j < 4) ? 0 : (SBLK * 256)) + blockIdx.x * 256 + c] = v;
    }
  }
}

// Stage B: 2 blocks (stat = blockIdx); thread c sums over SBLK partials, coalesced.
__global__ __launch_bounds__(256) void k_bnred(const float* __restrict__ part,
                                               float* __restrict__ sums) {
  int c = threadIdx.x;
  const float* p = part + blockIdx.x * (SBLK * 256);
  float s0 = 0.f, s1 = 0.f, s2 = 0.f, s3 = 0.f;
  for (int b = 0; b < SBLK; b += 4) {
    s0 += p[(b + 0) * 256 + c];
    s1 += p[(b + 1) * 256 + c];
    s2 += p[(b + 2) * 256 + c];
    s3 += p[(b + 3) * 256 + c];
  }
  sums[blockIdx.x * HH + c] = (s0 + s1) + (s2 + s3);
}

// y = bf16(relu(x*scale + shift)); scale/shift computed per-block from raw sums
__global__ __launch_bounds__(256) void k_bnrc(const unsigned short* __restrict__ X,
                                              const float* __restrict__ sums,
                                              const float* __restrict__ g,
                                              const float* __restrict__ be,
                                              unsigned short* __restrict__ out, int n4) {
  __shared__ float sc[HH], sh[HH];
  int t = threadIdx.x;
  {
    float inv = 1.f / (float)NN;
    float mean = sums[t] * inv;
    float var = sums[HH + t] * inv - mean * mean;
    float s = g[t] * rsqrtf(var + 1e-5f);
    sc[t] = s;
    sh[t] = be[t] - mean * s;
  }
  __syncthreads();
  for (int i = blockIdx.x * 256 + t; i < n4; i += gridDim.x * 256) {
    f32x4 x = bf4_to_f32(((const ushort4*)X)[i]);
    int c0 = (i * 4) & (HH - 1);
    ushort4 o;
    o.x = f2bf(fmaxf(x.x * sc[c0 + 0] + sh[c0 + 0], 0.f));
    o.y = f2bf(fmaxf(x.y * sc[c0 + 1] + sh[c0 + 1], 0.f));
    o.z = f2bf(fmaxf(x.z * sc[c0 + 2] + sh[c0 + 2], 0.f));
    o.w = f2bf(fmaxf(x.w * sc[c0 + 3] + sh[c0 + 3], 0.f));
    ((ushort4*)out)[i] = o;
  }
}

// ---------------- GEMM: C(MxNn) = A(MxK,bf16) * Bt(NnxK,bf16)^T + bias ----------------
// 128x128 tile, BK=32, 4 waves (2x2), each wave 4x4 grid of 16x16x32 MFMAs.
// OUTB=1: write bf16; OUTB=0: write fp32. gather: A row remap (head on idx rows).
template <int OUTB>
__global__ __launch_bounds__(256, 2) void k_gemm(const unsigned short* __restrict__ A,
                                                 const unsigned short* __restrict__ Bt,
                                                 const float* __restrict__ bias,
                                                 void* __restrict__ Cv,
                                                 int M, int K, int Nn,
                                                 const int* __restrict__ gather) {
  __shared__ unsigned short lA[128 * 32];  // 8 KB, rows of 64B
  __shared__ unsigned short lB[128 * 32];  // 8 KB
  const int tid = threadIdx.x;
  const int wave = tid >> 6, lane = tid & 63;
  const int m0 = blockIdx.x * 128, n0 = blockIdx.y * 128;
  const int wm = (wave >> 1) * 64, wn = (wave & 1) * 64;
  const int lhi = lane >> 4, llo = lane & 15;

  // staging geometry: per issue a wave covers 16 rows x 32 cols (64B rows, 4 lanes/row)
  const int srow = wave * 16 + (lane >> 2);
  const int scol = (lane & 3) * 8;
  int ar0 = m0 + srow, ar1 = m0 + 64 + srow;
  ar0 = ar0 < M ? ar0 : 0;
  ar1 = ar1 < M ? ar1 : 0;
  if (gather) { ar0 = gather[ar0]; ar1 = gather[ar1]; }
  const unsigned short* pA0 = A + (size_t)ar0 * K + scol;
  const unsigned short* pA1 = A + (size_t)ar1 * K + scol;
  const unsigned short* pB0 = Bt + (size_t)(n0 + srow) * K + scol;
  const unsigned short* pB1 = Bt + (size_t)(n0 + 64 + srow) * K + scol;
  unsigned short* dA0 = lA + (wave * 16) * 32;
  unsigned short* dA1 = lA + (64 + wave * 16) * 32;
  unsigned short* dB0 = lB + (wave * 16) * 32;
  unsigned short* dB1 = lB + (64 + wave * 16) * 32;

  f32x4 zero = {0.f, 0.f, 0.f, 0.f};
  f32x4 acc[4][4];
#pragma unroll
  for (int i = 0; i < 4; ++i)
#pragma unroll
    for (int j = 0; j < 4; ++j) acc[i][j] = zero;

  for (int k0 = 0; k0 < K; k0 += 32) {
    gload_lds16(pA0 + k0, dA0);
    gload_lds16(pA1 + k0, dA1);
    gload_lds16(pB0 + k0, dB0);
    gload_lds16(pB1 + k0, dB1);
    __syncthreads();  // drains vmcnt -> LDS valid
    bf16x8 af[4], bfv[4];
#pragma unroll
    for (int mt = 0; mt < 4; ++mt)
      af[mt] = *(const bf16x8*)(lA + (wm + mt * 16 + llo) * 32 + lhi * 8);
#pragma unroll
    for (int nt = 0; nt < 4; ++nt)
      bfv[nt] = *(const bf16x8*)(lB + (wn + nt * 16 + llo) * 32 + lhi * 8);
#pragma unroll
    for (int mt = 0; mt < 4; ++mt)
#pragma unroll
      for (int nt = 0; nt < 4; ++nt)
        acc[mt][nt] = __builtin_amdgcn_mfma_f32_16x16x32_bf16(af[mt], bfv[nt], acc[mt][nt], 0, 0, 0);
    __syncthreads();  // all reads done before next stage
  }

#pragma unroll
  for (int nt = 0; nt < 4; ++nt) {
    int cn = n0 + wn + nt * 16 + llo;
    float bv = bias ? bias[cn] : 0.f;
#pragma unroll
    for (int mt = 0; mt < 4; ++mt) {
      int cm0 = m0 + wm + mt * 16 + lhi * 4;
#pragma unroll
      for (int r = 0; r < 4; ++r) {
        int cm = cm0 + r;
        if (cm < M) {
          float v = acc[mt][nt][r] + bv;
          if (OUTB)
            ((unsigned short*)Cv)[(size_t)cm * Nn + cn] = f2bf(v);
          else
            ((float*)Cv)[(size_t)cm * Nn + cn] = v;
        }
      }
    }
  }
}

extern "C" void kernel_launch(void* const* d_in, const int* in_sizes, int n_in,
                              void* d_out, int out_size, void* d_ws, size_t ws_size,
                              hipStream_t stream) {
  const float* features = (const float*)d_in[0];
  const float* edge_vals = (const float*)d_in[1];
  const float* W1 = (const float*)d_in[2];
  const float* db1 = (const float*)d_in[3];
  // d_in[4] = b1  — annihilated by training-mode BN (constant per column before mean-subtract)
  const float* g1 = (const float*)d_in[5];
  const float* be1 = (const float*)d_in[6];
  const float* W2 = (const float*)d_in[7];
  // d_in[8] = b2  — annihilated by BN
  const float* g2 = (const float*)d_in[9];
  const float* be2 = (const float*)d_in[10];
  const float* Wf = (const float*)d_in[11];
  const float* bfb = (const float*)d_in[12];
  const int* erows = (const int*)d_in[13];
  const int* ecols = (const int*)d_in[14];
  const int* idx = (const int*)d_in[15];
  const int M3 = in_sizes[15];
  (void)n_in; (void)out_size; (void)ws_size;

  char* ws = (char*)d_ws;
  size_t off = 0;
  auto alloc = [&](size_t bytes) -> void* {
    void* p = (void*)(ws + off);
    off += (bytes + 255) & ~(size_t)255;
    return p;
  };
  unsigned short* Xb = (unsigned short*)alloc((size_t)NN * HH * 2);  // features / hidden (bf16)
  unsigned short* Ab = (unsigned short*)alloc((size_t)NN * HH * 2);  // gemm out (bf16)
  unsigned short* Yb = (unsigned short*)alloc((size_t)NN * HH * 2);  // spmm out (bf16)
  unsigned short* W1t = (unsigned short*)alloc((size_t)FF * HH * 2);
  unsigned short* W2t = (unsigned short*)alloc((size_t)HH * HH * 2);
  unsigned short* Wft = (unsigned short*)alloc((size_t)HH * LL * 2);
  int* cursor = (int*)alloc((size_t)NN * 4);
  int* cnt = (int*)alloc((size_t)NN * 4);
  unsigned int* csr = (unsigned int*)alloc((size_t)EE * 4);
  float* part = (float*)alloc((size_t)2 * SBLK * 256 * 4);  // bn partials
  float* stats = (float*)alloc(4 * HH * 4 + 256);  // sums1|sums2|total
  float* sums1 = stats;
  float* sums2 = stats + 2 * HH;
  int* total = (int*)(stats + 4 * HH);

  hipMemsetAsync(cnt, 0, (size_t)NN * 4, stream);
  hipMemsetAsync(total, 0, 256, stream);

  // all dtype conversions in one launch
  k_casts<<<13140, 256, 0, stream>>>(features, Xb, W1, W1t, W2, W2t, Wf, Wft);

  // CSR build (reused by both SpMMs); row bases via unordered atomic allocation
  k_hist<<<(EE + 255) / 256, 256, 0, stream>>>(erows, cnt, EE);
  k_alloc<<<(NN + 255) / 256, 256, 0, stream>>>(cnt, cursor, total, NN);
  k_fill<<<(EE + 255) / 256, 256, 0, stream>>>(erows, ecols, edge_vals, cursor, csr, EE);
  // after k_fill: cursor[row] == row end

  // layer 1
  k_gemm<1><<<dim3((NN + 127) / 128, HH / 128), 256, 0, stream>>>(Xb, W1t, db1, Ab, NN, FF, HH, nullptr);
  k_spmm<<<(NN + 3) / 4, 256, 0, stream>>>(Ab, cursor, cnt, csr, Yb, NN);
  k_bnstats<<<SBLK, 256, 0, stream>>>(Yb, part, NN);
  k_bnred<<<2, 256, 0, stream>>>(part, sums1);
  k_bnrc<<<2048, 256, 0, stream>>>(Yb, sums1, g1, be1, Xb, NN * HH / 4);

  // layer 2
  k_gemm<1><<<dim3((NN + 127) / 128, HH / 128), 256, 0, stream>>>(Xb, W2t, nullptr, Ab, NN, HH, HH, nullptr);
  k_spmm<<<(NN + 3) / 4, 256, 0, stream>>>(Ab, cursor, cnt, csr, Yb, NN);
  k_bnstats<<<SBLK, 256, 0, stream>>>(Yb, part, NN);
  k_bnred<<<2, 256, 0, stream>>>(part, sums2);
  k_bnrc<<<2048, 256, 0, stream>>>(Yb, sums2, g2, be2, Xb, NN * HH / 4);

  // head: only idx rows, C = H[idx] @ Wf + bf
  k_gemm<0><<<dim3((M3 + 127) / 128, LL / 128), 256, 0, stream>>>(Xb, Wft, bfb, d_out, M3, HH, LL, idx);
}

// Round 8
// 455.429 us; speedup vs baseline: 1.6184x; 1.0167x over previous
//
#include <hip/hip_runtime.h>
#include <stdint.h>

// Problem constants (fixed by the reference)
#define NN 50000
#define EE 800000
#define FF 256
#define HH 256
#define LL 128
#define SBLK 256   // bnstats stage-A blocks

typedef __bf16 bf16x8 __attribute__((ext_vector_type(8)));
typedef float  f32x4  __attribute__((ext_vector_type(4)));

typedef __attribute__((address_space(1))) unsigned int uint_as1;
typedef __attribute__((address_space(3))) unsigned int uint_as3;

__device__ __forceinline__ unsigned short f2bf(float f) {
  union { float f; unsigned int u; } v; v.f = f;
  unsigned int u = v.u;
  u += 0x7FFFu + ((u >> 16) & 1u);   // RTNE (finite inputs only)
  return (unsigned short)(u >> 16);
}

__device__ __forceinline__ float bf2f(unsigned short u) {
  union { unsigned int u; float f; } v;
  v.u = ((unsigned int)u) << 16;
  return v.f;
}

__device__ __forceinline__ f32x4 bf4_to_f32(ushort4 u) {
  f32x4 r;
  r.x = bf2f(u.x); r.y = bf2f(u.y); r.z = bf2f(u.z); r.w = bf2f(u.w);
  return r;
}

__device__ __forceinline__ void gload_lds16(const void* g, void* l) {
  __builtin_amdgcn_global_load_lds((const uint_as1*)g, (uint_as3*)l, 16, 0, 0);
}

// ---------------- fused setup: features cast + LDS-tiled weight transposes + zeroing ----
// grid: [0,12500) features | [12500,12516) W1 | [12516,12532) W2 | [12532,12540) Wf
//       [12540,12589) zero cnt | 12589 zero stats
__global__ __launch_bounds__(256) void k_casts(const float* __restrict__ features,
                                               unsigned short* __restrict__ Xb,
                                               const float* __restrict__ W1,
                                               unsigned short* __restrict__ W1t,
                                               const float* __restrict__ W2,
                                               unsigned short* __restrict__ W2t,
                                               const float* __restrict__ Wf,
                                               unsigned short* __restrict__ Wft,
                                               int* __restrict__ cnt,
                                               int* __restrict__ statz) {
  __shared__ float tl[64 * 65];
  int b = blockIdx.x, t = threadIdx.x;
  if (b < 12500) {
    int i = b * 256 + t;  // n4 = 3,200,000 exactly
    f32x4 x = ((const f32x4*)features)[i];
    ushort4 o;
    o.x = f2bf(x.x); o.y = f2bf(x.y); o.z = f2bf(x.z); o.w = f2bf(x.w);
    ((ushort4*)Xb)[i] = o;
  } else if (b < 12540) {
    const float* in;
    unsigned short* out;
    int Nin, k0, n0;
    if (b < 12516) {
      in = W1; out = W1t; Nin = HH;
      int tt = b - 12500; k0 = (tt >> 2) * 64; n0 = (tt & 3) * 64;
    } else if (b < 12532) {
      in = W2; out = W2t; Nin = HH;
      int tt = b - 12516; k0 = (tt >> 2) * 64; n0 = (tt & 3) * 64;
    } else {
      in = Wf; out = Wft; Nin = LL;
      int tt = b - 12532; k0 = (tt >> 1) * 64; n0 = (tt & 1) * 64;
    }
    // read 64x64 tile coalesced: tl[kr][nc] = in[(k0+kr)*Nin + n0+nc]
#pragma unroll
    for (int j = 0; j < 16; ++j) {
      int idx = j * 256 + t;
      int r = idx >> 6, c = idx & 63;
      tl[r * 65 + c] = in[(size_t)(k0 + r) * Nin + n0 + c];
    }
    __syncthreads();
    // write coalesced: out[(n0+r)*K + k0+c] = tl[c*65 + r]
#pragma unroll
    for (int j = 0; j < 16; ++j) {
      int idx = j * 256 + t;
      int r = idx >> 6, c = idx & 63;
      out[(size_t)(n0 + r) * HH + k0 + c] = f2bf(tl[c * 65 + r]);
    }
  } else if (b < 12589) {
    int base = (b - 12540) * 1024 + t * 4;
    if (base + 3 < NN) {
      int4 z = {0, 0, 0, 0};
      *(int4*)(cnt + base) = z;
    } else {
      for (int j = 0; j < 4; ++j)
        if (base + j < NN) cnt[base + j] = 0;
    }
  } else {
    for (int i = t; i < 4 * HH + 64; i += 256) statz[i] = 0;
  }
}

// ---------------- CSR build ----------------
__global__ __launch_bounds__(256) void k_hist(const int* __restrict__ rows,
                                              int* __restrict__ cnt, int E) {
  int i = blockIdx.x * 256 + threadIdx.x;
  if (i < E) atomicAdd(&cnt[rows[i]], 1);
}

// Unordered exclusive allocation: wave-scan of counts + one global atomic per wave.
__global__ __launch_bounds__(256) void k_alloc(const int* __restrict__ cnt,
                                               int* __restrict__ cursor,
                                               int* __restrict__ total, int n) {
  int i = blockIdx.x * 256 + threadIdx.x;
  int lane = threadIdx.x & 63;
  int c = (i < n) ? cnt[i] : 0;
  int incl = c;
#pragma unroll
  for (int off = 1; off < 64; off <<= 1) {
    int v = __shfl_up(incl, off, 64);
    if (lane >= off) incl += v;
  }
  int excl = incl - c;
  int wtot = __shfl(incl, 63, 64);
  int base = 0;
  if (lane == 0) base = atomicAdd(total, wtot);
  base = __shfl(base, 0, 64);
  if (i < n) cursor[i] = base + excl;
}

// CSR entry packed to 4B: (col << 16) | bf16(val). col < 50000 < 65536.
__global__ __launch_bounds__(256) void k_fill(const int* __restrict__ rows,
                                              const int* __restrict__ cols,
                                              const float* __restrict__ vals,
                                              int* __restrict__ cursor,
                                              unsigned int* __restrict__ csr, int E) {
  int i = blockIdx.x * 256 + threadIdx.x;
  if (i < E) {
    int p = atomicAdd(&cursor[rows[i]], 1);
    csr[p] = ((unsigned int)cols[i] << 16) | (unsigned int)f2bf(vals[i]);
  }
}

// ---------------- SpMM (bf16 in / bf16 out): Y[i] = sum_e val*X[col] ----------------
// One wave per row (lane = ushort4 -> full 512B row per gather), 4 edge streams.
// After k_fill, cursor[row] == row end; start = end - cnt[row].
__global__ __launch_bounds__(256) void k_spmm(const unsigned short* __restrict__ X,
                                              const int* __restrict__ endp,
                                              const int* __restrict__ cnt,
                                              const unsigned int* __restrict__ csr,
                                              unsigned short* __restrict__ Y, int n) {
  int row = blockIdx.x * 4 + (threadIdx.x >> 6);
  int lane = threadIdx.x & 63;
  if (row >= n) return;
  int e = endp[row];
  int s = e - cnt[row];
  f32x4 a0 = {0.f, 0.f, 0.f, 0.f};
  f32x4 a1 = a0, a2 = a0, a3 = a0;
  int p = s;
  int e4 = s + ((e - s) & ~3);
  for (; p < e4; p += 4) {
    unsigned int c0 = csr[p + 0], c1 = csr[p + 1], c2 = csr[p + 2], c3 = csr[p + 3];
    ushort4 x0 = ((const ushort4*)(X + (size_t)(c0 >> 16) * HH))[lane];
    ushort4 x1 = ((const ushort4*)(X + (size_t)(c1 >> 16) * HH))[lane];
    ushort4 x2 = ((const ushort4*)(X + (size_t)(c2 >> 16) * HH))[lane];
    ushort4 x3 = ((const ushort4*)(X + (size_t)(c3 >> 16) * HH))[lane];
    a0 += bf2f((unsigned short)c0) * bf4_to_f32(x0);
    a1 += bf2f((unsigned short)c1) * bf4_to_f32(x1);
    a2 += bf2f((unsigned short)c2) * bf4_to_f32(x2);
    a3 += bf2f((unsigned short)c3) * bf4_to_f32(x3);
  }
  for (; p < e; ++p) {
    unsigned int c0 = csr[p];
    ushort4 x0 = ((const ushort4*)(X + (size_t)(c0 >> 16) * HH))[lane];
    a0 += bf2f((unsigned short)c0) * bf4_to_f32(x0);
  }
  f32x4 a = (a0 + a1) + (a2 + a3);
  ushort4 o;
  o.x = f2bf(a.x); o.y = f2bf(a.y); o.z = f2bf(a.z); o.w = f2bf(a.w);
  ((ushort4*)(Y + (size_t)row * HH))[lane] = o;
}

// ---------------- BatchNorm stats, two-stage (atomic-light) ----------------
// Stage A: SBLK blocks; wave-per-4-rows ushort4 loads; LDS reduce (pad 9);
// block writes 512 partials contiguously. part layout: [stat(2)][SBLK][256]
__global__ __launch_bounds__(256) void k_bnstats(const unsigned short* __restrict__ X,
                                                 float* __restrict__ part, int n) {
  __shared__ float red[4][64][9];
  const int w = threadIdx.x >> 6, l = threadIdx.x & 63;
  f32x4 s = {0.f, 0.f, 0.f, 0.f}, s2 = {0.f, 0.f, 0.f, 0.f};
  for (int r = blockIdx.x * 4 + w; r < n; r += gridDim.x * 4) {
    f32x4 v = bf4_to_f32(((const ushort4*)(X + (size_t)r * HH))[l]);
    s += v;
    s2 += v * v;
  }
#pragma unroll
  for (int j = 0; j < 4; ++j) { red[w][l][j] = s[j]; red[w][l][4 + j] = s2[j]; }
  __syncthreads();
  if (threadIdx.x < 64) {
    int ll = threadIdx.x;
#pragma unroll
    for (int j = 0; j < 8; ++j) {
      float v = red[0][ll][j] + red[1][ll][j] + red[2][ll][j] + red[3][ll][j];
      int c = ll * 4 + (j & 3);
      part[((j < 4) ? 0 : (SBLK * 256)) + blockIdx.x * 256 + c] = v;
    }
  }
}

// Stage B: 16 blocks = 8 chunks x 2 stats; 32 partials each, 8-deep atomicAdd/col.
__global__ __launch_bounds__(256) void k_bnred(const float* __restrict__ part,
                                               float* __restrict__ sums) {
  int c = threadIdx.x;
  int stat = blockIdx.x >> 3, chunk = blockIdx.x & 7;
  const float* p = part + stat * (SBLK * 256) + chunk * 32 * 256;
  float s0 = 0.f, s1 = 0.f, s2 = 0.f, s3 = 0.f;
  for (int b = 0; b < 32; b += 4) {
    s0 += p[(b + 0) * 256 + c];
    s1 += p[(b + 1) * 256 + c];
    s2 += p[(b + 2) * 256 + c];
    s3 += p[(b + 3) * 256 + c];
  }
  atomicAdd(&sums[stat * HH + c], (s0 + s1) + (s2 + s3));
}

// y = bf16(relu(x*scale + shift)); scale/shift computed per-block from raw sums
__global__ __launch_bounds__(256) void k_bnrc(const unsigned short* __restrict__ X,
                                              const float* __restrict__ sums,
                                              const float* __restrict__ g,
                                              const float* __restrict__ be,
                                              unsigned short* __restrict__ out, int n4) {
  __shared__ float sc[HH], sh[HH];
  int t = threadIdx.x;
  {
    float inv = 1.f / (float)NN;
    float mean = sums[t] * inv;
    float var = sums[HH + t] * inv - mean * mean;
    float s = g[t] * rsqrtf(var + 1e-5f);
    sc[t] = s;
    sh[t] = be[t] - mean * s;
  }
  __syncthreads();
  for (int i = blockIdx.x * 256 + t; i < n4; i += gridDim.x * 256) {
    f32x4 x = bf4_to_f32(((const ushort4*)X)[i]);
    int c0 = (i * 4) & (HH - 1);
    ushort4 o;
    o.x = f2bf(fmaxf(x.x * sc[c0 + 0] + sh[c0 + 0], 0.f));
    o.y = f2bf(fmaxf(x.y * sc[c0 + 1] + sh[c0 + 1], 0.f));
    o.z = f2bf(fmaxf(x.z * sc[c0 + 2] + sh[c0 + 2], 0.f));
    o.w = f2bf(fmaxf(x.w * sc[c0 + 3] + sh[c0 + 3], 0.f));
    ((ushort4*)out)[i] = o;
  }
}

// ---------------- GEMM: C(MxNn) = A(MxK,bf16) * Bt(NnxK,bf16)^T + bias ----------------
// 128x128 tile, BK=64 (half the barriers of BK=32), 4 waves (2x2), each wave
// 4x4 grid of 16x16x32 MFMAs x 2 k-substeps. OUTB=1: bf16 out; 0: fp32 out.
// gather: A row remap (head on idx rows).
template <int OUTB>
__global__ __launch_bounds__(256, 2) void k_gemm(const unsigned short* __restrict__ A,
                                                 const unsigned short* __restrict__ Bt,
                                                 const float* __restrict__ bias,
                                                 void* __restrict__ Cv,
                                                 int M, int K, int Nn,
                                                 const int* __restrict__ gather) {
  __shared__ unsigned short lA[128 * 64];  // 16 KB, rows of 128B
  __shared__ unsigned short lB[128 * 64];  // 16 KB
  const int tid = threadIdx.x;
  const int wave = tid >> 6, lane = tid & 63;
  const int m0 = blockIdx.x * 128, n0 = blockIdx.y * 128;
  const int wm = (wave >> 1) * 64, wn = (wave & 1) * 64;
  const int lhi = lane >> 4, llo = lane & 15;

  // staging: 4 issues per wave per operand; issue j covers 8 rows x 64 cols
  // (128B rows, 8 lanes/row, 16B/lane)
  const int srow = lane >> 3;        // 0..7
  const int scol = (lane & 7) * 8;   // elem offset
  const unsigned short *pA[4], *pB[4];
#pragma unroll
  for (int j = 0; j < 4; ++j) {
    int base = (wave * 4 + j) * 8 + srow;
    int ar = m0 + base;
    ar = ar < M ? ar : 0;
    if (gather) ar = gather[ar];
    pA[j] = A + (size_t)ar * K + scol;
    pB[j] = Bt + (size_t)(n0 + base) * K + scol;
  }

  f32x4 zero = {0.f, 0.f, 0.f, 0.f};
  f32x4 acc[4][4];
#pragma unroll
  for (int i = 0; i < 4; ++i)
#pragma unroll
    for (int j = 0; j < 4; ++j) acc[i][j] = zero;

  for (int k0 = 0; k0 < K; k0 += 64) {
#pragma unroll
    for (int j = 0; j < 4; ++j) {
      gload_lds16(pA[j] + k0, lA + (wave * 4 + j) * 8 * 64);
      gload_lds16(pB[j] + k0, lB + (wave * 4 + j) * 8 * 64);
    }
    __syncthreads();  // drains vmcnt -> LDS valid
    bf16x8 af[2][4], bfv[2][4];
#pragma unroll
    for (int ks = 0; ks < 2; ++ks) {
#pragma unroll
      for (int mt = 0; mt < 4; ++mt)
        af[ks][mt] = *(const bf16x8*)(lA + (wm + mt * 16 + llo) * 64 + ks * 32 + lhi * 8);
#pragma unroll
      for (int nt = 0; nt < 4; ++nt)
        bfv[ks][nt] = *(const bf16x8*)(lB + (wn + nt * 16 + llo) * 64 + ks * 32 + lhi * 8);
    }
#pragma unroll
    for (int ks = 0; ks < 2; ++ks)
#pragma unroll
      for (int mt = 0; mt < 4; ++mt)
#pragma unroll
        for (int nt = 0; nt < 4; ++nt)
          acc[mt][nt] = __builtin_amdgcn_mfma_f32_16x16x32_bf16(af[ks][mt], bfv[ks][nt], acc[mt][nt], 0, 0, 0);
    __syncthreads();  // all reads done before next stage
  }

#pragma unroll
  for (int nt = 0; nt < 4; ++nt) {
    int cn = n0 + wn + nt * 16 + llo;
    float bv = bias ? bias[cn] : 0.f;
#pragma unroll
    for (int mt = 0; mt < 4; ++mt) {
      int cm0 = m0 + wm + mt * 16 + lhi * 4;
#pragma unroll
      for (int r = 0; r < 4; ++r) {
        int cm = cm0 + r;
        if (cm < M) {
          float v = acc[mt][nt][r] + bv;
          if (OUTB)
            ((unsigned short*)Cv)[(size_t)cm * Nn + cn] = f2bf(v);
          else
            ((float*)Cv)[(size_t)cm * Nn + cn] = v;
        }
      }
    }
  }
}

extern "C" void kernel_launch(void* const* d_in, const int* in_sizes, int n_in,
                              void* d_out, int out_size, void* d_ws, size_t ws_size,
                              hipStream_t stream) {
  const float* features = (const float*)d_in[0];
  const float* edge_vals = (const float*)d_in[1];
  const float* W1 = (const float*)d_in[2];
  const float* db1 = (const float*)d_in[3];
  // d_in[4] = b1  — annihilated by training-mode BN (constant per column before mean-subtract)
  const float* g1 = (const float*)d_in[5];
  const float* be1 = (const float*)d_in[6];
  const float* W2 = (const float*)d_in[7];
  // d_in[8] = b2  — annihilated by BN
  const float* g2 = (const float*)d_in[9];
  const float* be2 = (const float*)d_in[10];
  const float* Wf = (const float*)d_in[11];
  const float* bfb = (const float*)d_in[12];
  const int* erows = (const int*)d_in[13];
  const int* ecols = (const int*)d_in[14];
  const int* idx = (const int*)d_in[15];
  const int M3 = in_sizes[15];
  (void)n_in; (void)out_size; (void)ws_size;

  char* ws = (char*)d_ws;
  size_t off = 0;
  auto alloc = [&](size_t bytes) -> void* {
    void* p = (void*)(ws + off);
    off += (bytes + 255) & ~(size_t)255;
    return p;
  };
  unsigned short* Xb = (unsigned short*)alloc((size_t)NN * HH * 2);  // features / hidden (bf16)
  unsigned short* Ab = (unsigned short*)alloc((size_t)NN * HH * 2);  // gemm out (bf16)
  unsigned short* Yb = (unsigned short*)alloc((size_t)NN * HH * 2);  // spmm out (bf16)
  unsigned short* W1t = (unsigned short*)alloc((size_t)FF * HH * 2);
  unsigned short* W2t = (unsigned short*)alloc((size_t)HH * HH * 2);
  unsigned short* Wft = (unsigned short*)alloc((size_t)HH * LL * 2);
  int* cursor = (int*)alloc((size_t)NN * 4);
  int* cnt = (int*)alloc((size_t)NN * 4);
  unsigned int* csr = (unsigned int*)alloc((size_t)EE * 4);
  float* part = (float*)alloc((size_t)2 * SBLK * 256 * 4);  // bn partials
  float* stats = (float*)alloc(4 * HH * 4 + 256);  // sums1|sums2|total
  float* sums1 = stats;
  float* sums2 = stats + 2 * HH;
  int* total = (int*)(stats + 4 * HH);

  // all dtype conversions + workspace zeroing in one launch
  k_casts<<<12590, 256, 0, stream>>>(features, Xb, W1, W1t, W2, W2t, Wf, Wft,
                                     cnt, (int*)stats);

  // CSR build (reused by both SpMMs); row bases via unordered atomic allocation
  k_hist<<<(EE + 255) / 256, 256, 0, stream>>>(erows, cnt, EE);
  k_alloc<<<(NN + 255) / 256, 256, 0, stream>>>(cnt, cursor, total, NN);
  k_fill<<<(EE + 255) / 256, 256, 0, stream>>>(erows, ecols, edge_vals, cursor, csr, EE);
  // after k_fill: cursor[row] == row end

  // layer 1
  k_gemm<1><<<dim3((NN + 127) / 128, HH / 128), 256, 0, stream>>>(Xb, W1t, db1, Ab, NN, FF, HH, nullptr);
  k_spmm<<<(NN + 3) / 4, 256, 0, stream>>>(Ab, cursor, cnt, csr, Yb, NN);
  k_bnstats<<<SBLK, 256, 0, stream>>>(Yb, part, NN);
  k_bnred<<<16, 256, 0, stream>>>(part, sums1);
  k_bnrc<<<2048, 256, 0, stream>>>(Yb, sums1, g1, be1, Xb, NN * HH / 4);

  // layer 2
  k_gemm<1><<<dim3((NN + 127) / 128, HH / 128), 256, 0, stream>>>(Xb, W2t, nullptr, Ab, NN, HH, HH, nullptr);
  k_spmm<<<(NN + 3) / 4, 256, 0, stream>>>(Ab, cursor, cnt, csr, Yb, NN);
  k_bnstats<<<SBLK, 256, 0, stream>>>(Yb, part, NN);
  k_bnred<<<16, 256, 0, stream>>>(part, sums2);
  k_bnrc<<<2048, 256, 0, stream>>>(Yb, sums2, g2, be2, Xb, NN * HH / 4);

  // head: only idx rows, C = H[idx] @ Wf + bf
  k_gemm<0><<<dim3((M3 + 127) / 128, LL / 128), 256, 0, stream>>>(Xb, Wft, bfb, d_out, M3, HH, LL, idx);
}